// Round 10
// baseline (48.150 us; speedup 1.0000x reference)
//
#include <hip/hip_runtime.h>
#include <cstdint>
#include <cstddef>

typedef int v4i __attribute__((ext_vector_type(4)));

#define QMIN_F (-128.0f)
#define QMAX_F (127.0f)
#define SMALL_THR 6.1e-05f

#define WAITVM(n) asm volatile("s_waitcnt vmcnt(" #n ")" ::: "memory")
#define WAITLGKM0 asm volatile("s_waitcnt lgkmcnt(0)" ::: "memory")
#define SCHEDBAR __builtin_amdgcn_sched_barrier(0)

// ---------------------------------------------------------------------------
// Kernel 1: per-row dynamic quantization + fused weight pack (at BW roofline).
// ---------------------------------------------------------------------------
__global__ __launch_bounds__(256) void quant_rows_kernel(
    const float* __restrict__ x, signed char* __restrict__ q,
    float* __restrict__ scales, int* __restrict__ zps, int* __restrict__ sums,
    const int* __restrict__ w32, int* __restrict__ w8pk, int n4, int K) {
  const int gidx = blockIdx.x * 256 + threadIdx.x;
  if (gidx < n4) {
    v4i pv = *(const v4i*)(w32 + gidx * 4);
    w8pk[gidx] = (pv.x & 255) | ((pv.y & 255) << 8) | ((pv.z & 255) << 16) |
                 (pv.w << 24);
  }

  const int wave = threadIdx.x >> 6;
  const int lane = threadIdx.x & 63;
  const int row  = blockIdx.x * 4 + wave;
  const float* xr = x + (size_t)row * K;

  float4 v[4];
  float vmin = 0.0f, vmax = 0.0f, vsum = 0.0f;
#pragma unroll
  for (int j = 0; j < 4; ++j) {
    v[j] = *(const float4*)(xr + j * 256 + lane * 4);
    vmin = fminf(vmin, fminf(fminf(v[j].x, v[j].y), fminf(v[j].z, v[j].w)));
    vmax = fmaxf(vmax, fmaxf(fmaxf(v[j].x, v[j].y), fmaxf(v[j].z, v[j].w)));
    vsum += (v[j].x + v[j].y) + (v[j].z + v[j].w);
  }
#pragma unroll
  for (int off = 32; off >= 1; off >>= 1) {
    vmin = fminf(vmin, __shfl_xor(vmin, off));
    vmax = fmaxf(vmax, __shfl_xor(vmax, off));
    vsum += __shfl_xor(vsum, off);
  }

  float scale = (vmax - vmin) / (QMAX_F - QMIN_F);
  float isinf_f = isinf(1.0f / scale) ? 1.0f : 0.0f;
  if (scale == isinf_f) scale = 0.1f;
  float rmin = vmin, rmax = vmax;
  if (scale < SMALL_THR) {
    float amp = SMALL_THR / scale;
    scale = SMALL_THR;
    rmax *= amp;
    rmin *= amp;
  }
  float rdmin = rmin / scale, rdmax = rmax / scale;
  float err_min = 128.0f + fabsf(rdmin);
  float err_max = 127.0f + fabsf(rdmax);
  float zp0 = (err_min < err_max) ? (QMIN_F - rdmin) : (QMAX_F - rdmax);
  int zp = (int)rintf(zp0);
  if (zp0 < QMIN_F) zp = -128;
  if (zp0 > QMAX_F) zp = 127;
  float inv = 1.0f / scale;

  if (lane == 0) {
    scales[row] = scale;
    zps[row]    = zp;
    sums[row]   = (int)rintf(vsum * inv);
  }

  const float zpf = (float)zp;
  int* qi = (int*)(q + (size_t)row * K);
#pragma unroll
  for (int j = 0; j < 4; ++j) {
    float t0 = fminf(fmaxf(rintf(v[j].x * inv) + zpf, QMIN_F), QMAX_F);
    float t1 = fminf(fmaxf(rintf(v[j].y * inv) + zpf, QMIN_F), QMAX_F);
    float t2 = fminf(fmaxf(rintf(v[j].z * inv) + zpf, QMIN_F), QMAX_F);
    float t3 = fminf(fmaxf(rintf(v[j].w * inv) + zpf, QMIN_F), QMAX_F);
    int pack = ((int)t0 & 255) | (((int)t1 & 255) << 8) |
               (((int)t2 & 255) << 16) | ((int)t3 << 24);
    qi[j * 64 + lane] = pack;
  }
}

// ---------------------------------------------------------------------------
// Kernel 2: int8 GEMM + fused dequant. 1024 tiles of 128x128; grid 512;
// each block persistently processes 2 tiles (same N-strip, same XCD chunk)
// as ONE seamless 32-step pipeline -> tile-1 stores drain under tile-2's
// K-loop (half the write tail). 3-buffer LDS (48 KB) with stage lead-2 +
// REGISTER frag double-buffer: ds_reads for step t+1 issue before MFMA(t)
// and drain under it (lgkm wait off the critical path). One barrier/step
// (safe: per-step lgkmcnt(0) means concurrent stage writes hit
// buf[(t+2)%3] while laggards read buf[t%3] - disjoint).
// Swizzle slot^((row>>1)&3) both sides (R6: conflicts==0); plain stores
// (R6: nt = 1.5x write amplification); counted vmcnt, never 0 mid-loop.
// ---------------------------------------------------------------------------
__device__ __forceinline__ void gload_lds16(const void* g, void* l) {
  __builtin_amdgcn_global_load_lds(
      (const __attribute__((address_space(1))) void*)g,
      (__attribute__((address_space(3))) void*)l, 16, 0, 0);
}

// One K-tile stage: A 128x64 (2 chunks/thread) + B 128x64 (2 chunks/thread)
// = 4 outstanding vmem ops per thread per stage.
__device__ __forceinline__ void stage_tile(
    const signed char* __restrict__ q, const signed char* __restrict__ w,
    char* buf, int rowA0, int rowB0, int k0, int K, int tid) {
#pragma unroll
  for (int i = 0; i < 2; ++i) {
    int c  = (i << 8) + tid;
    int r  = c >> 2;
    int sl = (c & 3) ^ ((r >> 1) & 3);
    gload_lds16(q + (size_t)(rowA0 + r) * K + k0 + (sl << 4), buf + (c << 4));
  }
#pragma unroll
  for (int i = 0; i < 2; ++i) {
    int c  = (i << 8) + tid;
    int r  = c >> 2;
    int sl = (c & 3) ^ ((r >> 1) & 3);
    gload_lds16(w + (size_t)(rowB0 + r) * K + k0 + (sl << 4),
                buf + 8192 + (c << 4));
  }
}

__device__ __forceinline__ void read_frags(const char* bA, v4i* af, v4i* bf,
                                           int wrbase, int wcbase, int fr,
                                           int kb) {
  const char* bB = bA + 8192;
#pragma unroll
  for (int n = 0; n < 4; ++n) {
    int rb = wcbase + (n << 4) + fr;
    bf[n] = *(const v4i*)(bB + (rb << 6) + ((kb ^ ((rb >> 1) & 3)) << 4));
  }
#pragma unroll
  for (int m = 0; m < 4; ++m) {
    int ra = wrbase + (m << 4) + fr;
    af[m] = *(const v4i*)(bA + (ra << 6) + ((kb ^ ((ra >> 1) & 3)) << 4));
  }
}

__device__ __forceinline__ void mfma_cluster(v4i (&acc)[4][4], const v4i* af,
                                             const v4i* bf) {
  __builtin_amdgcn_s_setprio(1);
#pragma unroll
  for (int m = 0; m < 4; ++m)
#pragma unroll
    for (int n = 0; n < 4; ++n)
      acc[m][n] = __builtin_amdgcn_mfma_i32_16x16x64_i8(af[m], bf[n],
                                                        acc[m][n], 0, 0, 0);
  __builtin_amdgcn_s_setprio(0);
}

__device__ __forceinline__ void epilogue_store(
    v4i (&acc)[4][4], const float* __restrict__ scales,
    const int* __restrict__ zps, const int* __restrict__ sums,
    const float* __restrict__ bias, const float* __restrict__ w_scales,
    const int* __restrict__ w_zeros, const int* __restrict__ w_sums,
    float* __restrict__ out, int N, int baseM, int baseN, int lane) {
  const int qr = (lane >> 4) << 2;
  const int qc = lane & 15;
  float cb[4], cwsc[4];
  int cwz[4], cws[4];
#pragma unroll
  for (int n = 0; n < 4; ++n) {
    int col = baseN + (n << 4) + qc;
    cb[n]   = bias[col];
    cwsc[n] = w_scales[col];
    cwz[n]  = w_zeros[col];
    cws[n]  = w_sums[col];
  }
#pragma unroll
  for (int i = 0; i < 4; ++i) {
    const int m0 = baseM + (i << 4) + qr;
    float sc[4];
    int zp4[4], sm4[4];
#pragma unroll
    for (int j = 0; j < 4; ++j) {
      sc[j]  = scales[m0 + j];
      zp4[j] = zps[m0 + j];
      sm4[j] = sums[m0 + j];
    }
#pragma unroll
    for (int n = 0; n < 4; ++n) {
      const int col = baseN + (n << 4) + qc;
#pragma unroll
      for (int j = 0; j < 4; ++j) {
        int d    = acc[i][n][j];
        int temp = zp4[j] * cws[n] + sm4[j] * cwz[n];
        out[(size_t)(m0 + j) * N + col] =
            cb[n] + (float)(d - temp) * (sc[j] * cwsc[n]);
      }
    }
  }
}

__global__ __launch_bounds__(256, 2) void gemm_dequant_kernel(
    const signed char* __restrict__ q, const signed char* __restrict__ w,
    const float* __restrict__ scales, const int* __restrict__ zps,
    const int* __restrict__ sums, const float* __restrict__ bias,
    const float* __restrict__ w_scales, const int* __restrict__ w_zeros,
    const int* __restrict__ w_sums, float* __restrict__ out,
    int N, int K, int ntiles) {
  __shared__ char sh[3][16384];              // 3 bufs: A 8K | B 8K each
  const int tid  = threadIdx.x;
  const int lane = tid & 63;
  const int wave = tid >> 6;
  const int wrbase = (wave >> 1) << 6;
  const int wcbase = (wave & 1) << 6;
  const int fr = lane & 15;
  const int kb = lane >> 4;
  const int ntN = N >> 7;                    // 8
  // XCD chunking + persistent pairing: xcd owns tpx consecutive lins;
  // block handles lin0 and lin0+half (same tn -> shared B panel).
  const int tpx  = ntiles >> 3;              // 128
  const int half = tpx >> 1;                 // 64
  const int xcd  = (int)blockIdx.x & 7;
  const int idx  = (int)blockIdx.x >> 3;     // 0..half-1
  const int lin0 = xcd * tpx + idx;
  const int lin1 = lin0 + half;
  const int rowA0_0 = (lin0 / ntN) << 7, rowB0_0 = (lin0 % ntN) << 7;
  const int rowA0_1 = (lin1 / ntN) << 7, rowB0_1 = (lin1 % ntN) << 7;

#define STAGE(sidx, BUF)                                                \
  do {                                                                  \
    int _s = (sidx);                                                    \
    if (_s < 32) {                                                      \
      int _ra = (_s & 16) ? rowA0_1 : rowA0_0;                          \
      int _rb = (_s & 16) ? rowB0_1 : rowB0_0;                          \
      stage_tile(q, w, (BUF), _ra, _rb, (_s & 15) << 6, K, tid);        \
    }                                                                   \
  } while (0)

  v4i acc[4][4];
#pragma unroll
  for (int i = 0; i < 4; ++i)
#pragma unroll
    for (int j = 0; j < 4; ++j) {
      v4i z = {0, 0, 0, 0};
      acc[i][j] = z;
    }

  char* P0 = sh[0];
  char* P1 = sh[1];
  char* P2 = sh[2];

  v4i afA[4], bfA[4], afB[4], bfB[4];

  // Prologue: stage(0), stage(1); frags(0) -> set A.
  STAGE(0, P0);
  STAGE(1, P1);
  WAITVM(4);                                 // stage(0) complete
  __builtin_amdgcn_s_barrier();
  read_frags(P0, afA, bfA, wrbase, wcbase, fr, kb);
  WAITLGKM0;
  SCHEDBAR;

  for (int tt = 0; tt < 32; tt += 2) {
    // ---- step t = tt (even): MFMA on set A, prefetch frags(t+1) into B ----
    STAGE(tt + 2, P2);
    if (tt < 30) { WAITVM(4); } else { WAITVM(0); }
    __builtin_amdgcn_s_barrier();            // buf[(t+1)%3] ready for all
    read_frags(P1, afB, bfB, wrbase, wcbase, fr, kb);
    mfma_cluster(acc, afA, bfA);
    WAITLGKM0;                               // frags(t+1) landed (under MFMA)
    SCHEDBAR;

    // ---- step t = tt+1 (odd): MFMA on set B, prefetch frags(t+1) into A ---
    STAGE(tt + 3, P0);
    if (tt + 1 < 30) { WAITVM(4); } else { WAITVM(0); }
    __builtin_amdgcn_s_barrier();
    if (tt < 30) {
      read_frags(P2, afA, bfA, wrbase, wcbase, fr, kb);
    }
    mfma_cluster(acc, afB, bfB);
    WAITLGKM0;
    SCHEDBAR;

    // rotate buffers: (P0,P1,P2) <- (P2,P0,P1)
    char* tmp = P2;
    P2 = P1;
    P1 = P0;
    P0 = tmp;

    // tile-0 done after step 15 (tt==14): store + reset acc; stores drain
    // under tile-1's K-loop.
    if (tt == 14) {
      epilogue_store(acc, scales, zps, sums, bias, w_scales, w_zeros, w_sums,
                     out, N, rowA0_0 + wrbase, rowB0_0 + wcbase, lane);
#pragma unroll
      for (int i = 0; i < 4; ++i)
#pragma unroll
        for (int j = 0; j < 4; ++j) {
          v4i z = {0, 0, 0, 0};
          acc[i][j] = z;
        }
    }
  }

  epilogue_store(acc, scales, zps, sums, bias, w_scales, w_zeros, w_sums,
                 out, N, rowA0_1 + wrbase, rowB0_1 + wcbase, lane);
#undef STAGE
}

extern "C" void kernel_launch(void* const* d_in, const int* in_sizes, int n_in,
                              void* d_out, int out_size, void* d_ws, size_t ws_size,
                              hipStream_t stream) {
  const float* inp      = (const float*)d_in[0];
  const int*   qw32     = (const int*)d_in[1];   // int8 in ref -> int32 on device
  const float* bias     = (const float*)d_in[2];
  const float* w_scales = (const float*)d_in[3];
  const int*   w_zeros  = (const int*)d_in[4];
  const int*   w_sums   = (const int*)d_in[5];

  const int N = in_sizes[2];      // 1024
  const int K = in_sizes[1] / N;  // 1024
  const int M = in_sizes[0] / K;  // 16384

  float*       scales = (float*)d_ws;
  int*         zps    = (int*)((char*)d_ws + (size_t)M * 4);
  int*         sums   = (int*)((char*)d_ws + (size_t)M * 8);
  signed char* q      = (signed char*)((char*)d_ws + (size_t)M * 12);
  signed char* w8     = (signed char*)((char*)d_ws + (size_t)M * 12 + (size_t)M * K);

  const int n4 = (N * K) / 4;
  const int ntiles = (M / 128) * (N / 128);  // 1024 tiles
  const int nblk   = ntiles / 2;             // 512 persistent blocks (2/CU)
  quant_rows_kernel<<<M / 4, 256, 0, stream>>>(inp, q, scales, zps, sums,
                                               qw32, (int*)w8, n4, K);
  gemm_dequant_kernel<<<nblk, 256, 0, stream>>>(
      q, w8, scales, zps, sums, bias, w_scales, w_zeros, w_sums,
      (float*)d_out, N, K, ntiles);
}

// Round 12
// 46.527 us; speedup vs baseline: 1.0349x; 1.0349x over previous
//
#include <hip/hip_runtime.h>
#include <cstdint>
#include <cstddef>

typedef int v4i __attribute__((ext_vector_type(4)));

#define QMIN_F (-128.0f)
#define QMAX_F (127.0f)
#define SMALL_THR 6.1e-05f

#define WAITVM(n) asm volatile("s_waitcnt vmcnt(" #n ")" ::: "memory")
#define SCHEDBAR __builtin_amdgcn_sched_barrier(0)

// ---------------------------------------------------------------------------
// Kernel 1: per-row dynamic quantization + fused weight pack (at BW roofline).
// ---------------------------------------------------------------------------
__global__ __launch_bounds__(256) void quant_rows_kernel(
    const float* __restrict__ x, signed char* __restrict__ q,
    float* __restrict__ scales, int* __restrict__ zps, int* __restrict__ sums,
    const int* __restrict__ w32, int* __restrict__ w8pk, int n4, int K) {
  const int gidx = blockIdx.x * 256 + threadIdx.x;
  if (gidx < n4) {
    v4i pv = *(const v4i*)(w32 + gidx * 4);
    w8pk[gidx] = (pv.x & 255) | ((pv.y & 255) << 8) | ((pv.z & 255) << 16) |
                 (pv.w << 24);
  }

  const int wave = threadIdx.x >> 6;
  const int lane = threadIdx.x & 63;
  const int row  = blockIdx.x * 4 + wave;
  const float* xr = x + (size_t)row * K;

  float4 v[4];
  float vmin = 0.0f, vmax = 0.0f, vsum = 0.0f;
#pragma unroll
  for (int j = 0; j < 4; ++j) {
    v[j] = *(const float4*)(xr + j * 256 + lane * 4);
    vmin = fminf(vmin, fminf(fminf(v[j].x, v[j].y), fminf(v[j].z, v[j].w)));
    vmax = fmaxf(vmax, fmaxf(fmaxf(v[j].x, v[j].y), fmaxf(v[j].z, v[j].w)));
    vsum += (v[j].x + v[j].y) + (v[j].z + v[j].w);
  }
#pragma unroll
  for (int off = 32; off >= 1; off >>= 1) {
    vmin = fminf(vmin, __shfl_xor(vmin, off));
    vmax = fmaxf(vmax, __shfl_xor(vmax, off));
    vsum += __shfl_xor(vsum, off);
  }

  float scale = (vmax - vmin) / (QMAX_F - QMIN_F);
  float isinf_f = isinf(1.0f / scale) ? 1.0f : 0.0f;
  if (scale == isinf_f) scale = 0.1f;
  float rmin = vmin, rmax = vmax;
  if (scale < SMALL_THR) {
    float amp = SMALL_THR / scale;
    scale = SMALL_THR;
    rmax *= amp;
    rmin *= amp;
  }
  float rdmin = rmin / scale, rdmax = rmax / scale;
  float err_min = 128.0f + fabsf(rdmin);
  float err_max = 127.0f + fabsf(rdmax);
  float zp0 = (err_min < err_max) ? (QMIN_F - rdmin) : (QMAX_F - rdmax);
  int zp = (int)rintf(zp0);
  if (zp0 < QMIN_F) zp = -128;
  if (zp0 > QMAX_F) zp = 127;
  float inv = 1.0f / scale;

  if (lane == 0) {
    scales[row] = scale;
    zps[row]    = zp;
    sums[row]   = (int)rintf(vsum * inv);
  }

  const float zpf = (float)zp;
  int* qi = (int*)(q + (size_t)row * K);
#pragma unroll
  for (int j = 0; j < 4; ++j) {
    float t0 = fminf(fmaxf(rintf(v[j].x * inv) + zpf, QMIN_F), QMAX_F);
    float t1 = fminf(fmaxf(rintf(v[j].y * inv) + zpf, QMIN_F), QMAX_F);
    float t2 = fminf(fmaxf(rintf(v[j].z * inv) + zpf, QMIN_F), QMAX_F);
    float t3 = fminf(fmaxf(rintf(v[j].w * inv) + zpf, QMIN_F), QMAX_F);
    int pack = ((int)t0 & 255) | (((int)t1 & 255) << 8) |
               (((int)t2 & 255) << 16) | ((int)t3 << 24);
    qi[j * 64 + lane] = pack;
  }
}

// ---------------------------------------------------------------------------
// Kernel 2: int8 GEMM + fused dequant, fine-interleaved phase schedule
// (T3+T4+T5): BM=256, BN=128, BK=64, 512 thr, 8 waves (4M x 2N, wave-out
// 64x64, acc 64 VGPR). Per K-tile, 4 MFMA quadrants; next quadrant's
// ds_reads ISSUE before current quadrant's MFMA cluster; sched_barrier(0)
// pins phase boundaries; setprio(1) per cluster. Stage lead-2; counted
// WAITVM(3) with TAIL special-case (R11 bug: unconditional vmcnt(3) at
// t=NT-1 let the last tile's own 3 loads fly uncompleted -> race).
// LDS 48 KB -> 2 blocks/CU. Swizzle slot^((row>>1)&3) both sides (R6:
// conflicts==0); plain stores (R6: nt = 1.5x amplification).
// ---------------------------------------------------------------------------
__device__ __forceinline__ void gload_lds16(const void* g, void* l) {
  __builtin_amdgcn_global_load_lds(
      (const __attribute__((address_space(1))) void*)g,
      (__attribute__((address_space(3))) void*)l, 16, 0, 0);
}

#define BUFA_SZ 16384   // 256 rows x 64 B
#define BUFB_SZ 8192    // 128 rows x 64 B

// 3 gloads per thread: A 1024 chunks (2/thr), B 512 chunks (1/thr).
__device__ __forceinline__ void stage_tile(
    const signed char* __restrict__ q, const signed char* __restrict__ w,
    char* buf, int rowA0, int rowB0, int k0, int K, int tid) {
#pragma unroll
  for (int i = 0; i < 2; ++i) {
    int c  = (i << 9) + tid;
    int r  = c >> 2;
    int sl = (c & 3) ^ ((r >> 1) & 3);
    gload_lds16(q + (size_t)(rowA0 + r) * K + k0 + (sl << 4), buf + (c << 4));
  }
  {
    int c  = tid;
    int r  = c >> 2;
    int sl = (c & 3) ^ ((r >> 1) & 3);
    gload_lds16(w + (size_t)(rowB0 + r) * K + k0 + (sl << 4),
                buf + BUFA_SZ + (c << 4));
  }
}

__device__ __forceinline__ v4i lds_frag(const char* base, int row, int kb) {
  return *(const v4i*)(base + (row << 6) + ((kb ^ ((row >> 1) & 3)) << 4));
}

__global__ __launch_bounds__(512, 4) void gemm_dequant_kernel(
    const signed char* __restrict__ q, const signed char* __restrict__ w,
    const float* __restrict__ scales, const int* __restrict__ zps,
    const int* __restrict__ sums, const float* __restrict__ bias,
    const float* __restrict__ w_scales, const int* __restrict__ w_zeros,
    const int* __restrict__ w_sums, float* __restrict__ out,
    int N, int K, int nblk) {
  __shared__ char sh[2][BUFA_SZ + BUFB_SZ];  // 48 KB
  const int tid  = threadIdx.x;
  const int lane = tid & 63;
  const int wave = tid >> 6;                 // 0..7
  const int wrbase = (wave >> 1) << 6;       // 4 M-quarters of 64 rows
  const int wcbase = (wave & 1) << 6;        // 2 N-halves of 64 cols
  const int fr = lane & 15;
  const int kb = lane >> 4;
  const int ntN = N >> 7;                    // 8
  // XCD chunk (nblk % 8 == 0): 64 lins/XCD -> A 2 MB + w 1 MB fit 4 MB L2.
  const int per = nblk >> 3;
  const int lin = ((int)blockIdx.x & 7) * per + ((int)blockIdx.x >> 3);
  const int rowA0 = (lin / ntN) << 8;        // BM=256
  const int rowB0 = (lin % ntN) << 7;        // BN=128

  v4i acc[4][4];
#pragma unroll
  for (int i = 0; i < 4; ++i)
#pragma unroll
    for (int j = 0; j < 4; ++j) {
      v4i z = {0, 0, 0, 0};
      acc[i][j] = z;
    }

  const int NT = K >> 6;                     // 16
  stage_tile(q, w, sh[0], rowA0, rowB0, 0, K, tid);
  stage_tile(q, w, sh[1], rowA0, rowB0, 64, K, tid);

  for (int t = 0; t < NT; ++t) {
    // Tail-aware counted wait: at t=NT-1 the only outstanding loads are
    // stage(NT-1)'s own 3 -> must drain fully (R11 bug).
    if (t + 1 < NT) { WAITVM(3); } else { WAITVM(0); }
    __builtin_amdgcn_s_barrier();            // all waves' DMA for tile t done

    const char* bA = sh[t & 1];
    const char* bB = bA + BUFA_SZ;

    // ---- phase 0: read q0 frags ----
    v4i af0 = lds_frag(bA, wrbase + 0  + fr, kb);
    v4i af1 = lds_frag(bA, wrbase + 16 + fr, kb);
    v4i bf0 = lds_frag(bB, wcbase + 0  + fr, kb);
    v4i bf1 = lds_frag(bB, wcbase + 16 + fr, kb);
    SCHEDBAR;
    // ---- phase 1: issue q1 reads, MFMA q0 ----
    v4i bf2 = lds_frag(bB, wcbase + 32 + fr, kb);
    v4i bf3 = lds_frag(bB, wcbase + 48 + fr, kb);
    __builtin_amdgcn_s_setprio(1);
    acc[0][0] = __builtin_amdgcn_mfma_i32_16x16x64_i8(af0, bf0, acc[0][0], 0, 0, 0);
    acc[0][1] = __builtin_amdgcn_mfma_i32_16x16x64_i8(af0, bf1, acc[0][1], 0, 0, 0);
    acc[1][0] = __builtin_amdgcn_mfma_i32_16x16x64_i8(af1, bf0, acc[1][0], 0, 0, 0);
    acc[1][1] = __builtin_amdgcn_mfma_i32_16x16x64_i8(af1, bf1, acc[1][1], 0, 0, 0);
    __builtin_amdgcn_s_setprio(0);
    SCHEDBAR;
    // ---- phase 2: issue q2 reads, MFMA q1 ----
    v4i af2 = lds_frag(bA, wrbase + 32 + fr, kb);
    v4i af3 = lds_frag(bA, wrbase + 48 + fr, kb);
    __builtin_amdgcn_s_setprio(1);
    acc[0][2] = __builtin_amdgcn_mfma_i32_16x16x64_i8(af0, bf2, acc[0][2], 0, 0, 0);
    acc[0][3] = __builtin_amdgcn_mfma_i32_16x16x64_i8(af0, bf3, acc[0][3], 0, 0, 0);
    acc[1][2] = __builtin_amdgcn_mfma_i32_16x16x64_i8(af1, bf2, acc[1][2], 0, 0, 0);
    acc[1][3] = __builtin_amdgcn_mfma_i32_16x16x64_i8(af1, bf3, acc[1][3], 0, 0, 0);
    __builtin_amdgcn_s_setprio(0);
    SCHEDBAR;
    // ---- phase 3: MFMA q2 + q3 ----
    __builtin_amdgcn_s_setprio(1);
    acc[2][0] = __builtin_amdgcn_mfma_i32_16x16x64_i8(af2, bf0, acc[2][0], 0, 0, 0);
    acc[2][1] = __builtin_amdgcn_mfma_i32_16x16x64_i8(af2, bf1, acc[2][1], 0, 0, 0);
    acc[3][0] = __builtin_amdgcn_mfma_i32_16x16x64_i8(af3, bf0, acc[3][0], 0, 0, 0);
    acc[3][1] = __builtin_amdgcn_mfma_i32_16x16x64_i8(af3, bf1, acc[3][1], 0, 0, 0);
    acc[2][2] = __builtin_amdgcn_mfma_i32_16x16x64_i8(af2, bf2, acc[2][2], 0, 0, 0);
    acc[2][3] = __builtin_amdgcn_mfma_i32_16x16x64_i8(af2, bf3, acc[2][3], 0, 0, 0);
    acc[3][2] = __builtin_amdgcn_mfma_i32_16x16x64_i8(af3, bf2, acc[3][2], 0, 0, 0);
    acc[3][3] = __builtin_amdgcn_mfma_i32_16x16x64_i8(af3, bf3, acc[3][3], 0, 0, 0);
    __builtin_amdgcn_s_setprio(0);
    SCHEDBAR;

    __builtin_amdgcn_s_barrier();            // all reads of buf[t&1] consumed
    if (t + 2 < NT)                          // refill just-freed buffer
      stage_tile(q, w, sh[t & 1], rowA0, rowB0, (t + 2) << 6, K, tid);
  }

  // Epilogue: C/D layout col = lane&15, row = (lane>>4)*4 + reg.
  const int baseM = rowA0 + wrbase;
  const int baseN = rowB0 + wcbase;
  const int qr = (lane >> 4) << 2;
  const int qc = lane & 15;
  float cb[4], cwsc[4];
  int cwz[4], cws[4];
#pragma unroll
  for (int n = 0; n < 4; ++n) {
    int col = baseN + (n << 4) + qc;
    cb[n]   = bias[col];
    cwsc[n] = w_scales[col];
    cwz[n]  = w_zeros[col];
    cws[n]  = w_sums[col];
  }
#pragma unroll
  for (int i = 0; i < 4; ++i) {
    const int m0 = baseM + (i << 4) + qr;
    float sc[4];
    int zp4[4], sm4[4];
#pragma unroll
    for (int j = 0; j < 4; ++j) {
      sc[j]  = scales[m0 + j];
      zp4[j] = zps[m0 + j];
      sm4[j] = sums[m0 + j];
    }
#pragma unroll
    for (int n = 0; n < 4; ++n) {
      const int col = baseN + (n << 4) + qc;
#pragma unroll
      for (int j = 0; j < 4; ++j) {
        int d    = acc[i][n][j];
        int temp = zp4[j] * cws[n] + sm4[j] * cwz[n];
        out[(size_t)(m0 + j) * N + col] =
            cb[n] + (float)(d - temp) * (sc[j] * cwsc[n]);
      }
    }
  }
}

extern "C" void kernel_launch(void* const* d_in, const int* in_sizes, int n_in,
                              void* d_out, int out_size, void* d_ws, size_t ws_size,
                              hipStream_t stream) {
  const float* inp      = (const float*)d_in[0];
  const int*   qw32     = (const int*)d_in[1];   // int8 in ref -> int32 on device
  const float* bias     = (const float*)d_in[2];
  const float* w_scales = (const float*)d_in[3];
  const int*   w_zeros  = (const int*)d_in[4];
  const int*   w_sums   = (const int*)d_in[5];

  const int N = in_sizes[2];      // 1024
  const int K = in_sizes[1] / N;  // 1024
  const int M = in_sizes[0] / K;  // 16384

  float*       scales = (float*)d_ws;
  int*         zps    = (int*)((char*)d_ws + (size_t)M * 4);
  int*         sums   = (int*)((char*)d_ws + (size_t)M * 8);
  signed char* q      = (signed char*)((char*)d_ws + (size_t)M * 12);
  signed char* w8     = (signed char*)((char*)d_ws + (size_t)M * 12 + (size_t)M * K);

  const int n4 = (N * K) / 4;
  const int nblk = (M / 256) * (N / 128);    // 512 blocks = 2/CU
  quant_rows_kernel<<<M / 4, 256, 0, stream>>>(inp, q, scales, zps, sums,
                                               qw32, (int*)w8, n4, K);
  gemm_dequant_kernel<<<nblk, 512, 0, stream>>>(
      q, w8, scales, zps, sums, bias, w_scales, w_zeros, w_sums,
      (float*)d_out, N, K, nblk);
}